// Round 2
// 2190.628 us; speedup vs baseline: 1.0180x; 1.0180x over previous
//
#include <hip/hip_runtime.h>
#include <math.h>

// ScaledDotProductAttention: B=4,H=16,S=2048,D=64, fp32 in, outputs (out, attn) fp32.
// out region: [0, B*H*S*D), attn region: [B*H*S*D, B*H*S*D + B*H*S*S).
//
// Round 2b design (round-2 resubmit with ws_size guard + fallback):
//  - Prep kernels (into d_ws): K -> bf16 hi/lo split (done ONCE, not per-wg),
//    V -> bf16 vT[d][s], mask -> bit-packed mbT[b][chunk][row] (67MB -> 2MB).
//  - Main kernel: 1 wg (4 waves) per (bh, 16-q stripe); wave w owns j-tiles
//    w*32..w*32+31. SWAPPED QK mfma (A=K, B=Q) => C[m=j][n=q]: lane = q row.
//    Mask = 1 coalesced dword/tile; attn store = float4 nontemporal.
//  - Pass 1: online (m,l) only (no score storage => low VGPR => 4 blocks/CU).
//  - Pass 2: recompute tile, p = exp2(s-m)*linv, write attn, repack p to PV
//    B-fragment with shfl_xor(16/32) (no LDS), accumulate out^T = V^T * P^T
//    per-wave partials; single LDS reduction at the end. No barriers in loops.
//  - exp2 domain: fold log2(e)/TEMPERATURE into q scale.
//  - If ws_size < required (52.4MB), fall back to the round-0 kernel (verified
//    2230us) instead of corrupting memory.

#define SEQ 2048
#define HD 64
#define NH 16
#define NB 4
#define BHN (NB * NH)
#define KN ((size_t)BHN * SEQ * HD)  // 8388608 elems
#define MASK_FILL -1e9f
#define QSCALE (0.125f * 1.44269504088896f)  // 1/TEMPERATURE * log2(e)
#define WS_REQUIRED (3 * KN * sizeof(__bf16) + (size_t)NB * 64 * SEQ * sizeof(unsigned))

typedef float floatx4 __attribute__((ext_vector_type(4)));
typedef __bf16 bf16x8 __attribute__((ext_vector_type(8)));

__device__ __forceinline__ void split8(const float4 a, const float4 b, const float s,
                                       bf16x8& hi, bf16x8& lo) {
  float f[8] = {a.x * s, a.y * s, a.z * s, a.w * s,
                b.x * s, b.y * s, b.z * s, b.w * s};
#pragma unroll
  for (int j = 0; j < 8; ++j) {
    __bf16 h = (__bf16)f[j];
    hi[j] = h;
    lo[j] = (__bf16)(f[j] - (float)h);
  }
}

__device__ __forceinline__ unsigned pkbf(float a, float b) {
  union { __bf16 h[2]; unsigned u; } x;
  x.h[0] = (__bf16)a;
  x.h[1] = (__bf16)b;
  return x.u;
}

// ---------------- prep kernels ----------------

__global__ void prep_splitk(const float* __restrict__ kp, __bf16* __restrict__ khi,
                            __bf16* __restrict__ klo) {
  size_t i = ((size_t)blockIdx.x * 256 + threadIdx.x) * 8;
  float4 a = *(const float4*)(kp + i);
  float4 b = *(const float4*)(kp + i + 4);
  bf16x8 hi, lo;
  float f[8] = {a.x, a.y, a.z, a.w, b.x, b.y, b.z, b.w};
#pragma unroll
  for (int j = 0; j < 8; ++j) {
    __bf16 h = (__bf16)f[j];
    hi[j] = h;
    lo[j] = (__bf16)(f[j] - (float)h);
  }
  *(bf16x8*)(khi + i) = hi;
  *(bf16x8*)(klo + i) = lo;
}

__global__ void prep_vt(const float* __restrict__ vp, __bf16* __restrict__ vT) {
  __shared__ __bf16 tile[64][72];  // 64 s x 64 d, padded
  const int bhi = blockIdx.x >> 5;
  const int s0 = (blockIdx.x & 31) * 64;
  const int t = threadIdx.x;
  const float* vb = vp + (size_t)bhi * SEQ * HD + (size_t)s0 * HD;
#pragma unroll
  for (int c = 0; c < 4; ++c) {
    int ft = c * 256 + t;          // flat float4 index in 64x64 tile
    int sl = ft >> 4, d0 = (ft & 15) * 4;
    float4 x = *(const float4*)(vb + (size_t)sl * HD + d0);
    tile[sl][d0 + 0] = (__bf16)x.x;
    tile[sl][d0 + 1] = (__bf16)x.y;
    tile[sl][d0 + 2] = (__bf16)x.z;
    tile[sl][d0 + 3] = (__bf16)x.w;
  }
  __syncthreads();
  const int d = t >> 2, sc = (t & 3) * 16;
  __bf16* o = vT + (size_t)bhi * HD * SEQ + (size_t)d * SEQ + s0 + sc;
  bf16x8 v0, v1;
#pragma unroll
  for (int j = 0; j < 8; ++j) {
    v0[j] = tile[sc + j][d];
    v1[j] = tile[sc + 8 + j][d];
  }
  *(bf16x8*)o = v0;
  *(bf16x8*)(o + 8) = v1;
}

// mbT[b][c][row], c = j/32 chunk; bit (j&31) set => masked (fill -1e9)
__global__ void prep_mask(const int* __restrict__ mp, unsigned* __restrict__ mbT) {
  const int lane = threadIdx.x & 63;
  const int w = threadIdx.x >> 6;
  const size_t g0 = ((size_t)blockIdx.x * 4 + w) * 64;
  unsigned long long bits = __ballot(mp[g0 + lane] != 0);
  if (lane == 0) {
    const int b = (int)(g0 / ((size_t)SEQ * SEQ));
    const size_t rem = g0 % ((size_t)SEQ * SEQ);
    const int row = (int)(rem / SEQ);
    const int c = (int)(rem % SEQ) >> 5;
    mbT[((size_t)b * 64 + c) * SEQ + row] = (unsigned)bits;
    mbT[((size_t)b * 64 + c + 1) * SEQ + row] = (unsigned)(bits >> 32);
  }
}

// ---------------- main kernel ----------------

struct TileOut { unsigned d0, d1; };

// One 16-j tile: 6 MFMAs (bf16x3), mask, p = exp2(s-mf)*linv, attn float4 store,
// return the lane's 4 p-values packed as 2 bf16x2 dwords.
__device__ __forceinline__ TileOut do_tile(const __bf16* __restrict__ kh,
                                           const __bf16* __restrict__ kl,
                                           bf16x8 qhi0, bf16x8 qlo0, bf16x8 qhi1,
                                           bf16x8 qlo1, unsigned bits4, float mf,
                                           float linv, float* attn_addr) {
  bf16x8 kh0 = *(const bf16x8*)kh, kh1 = *(const bf16x8*)(kh + 32);
  bf16x8 kl0 = *(const bf16x8*)kl, kl1 = *(const bf16x8*)(kl + 32);
  floatx4 a = 0.f;
  a = __builtin_amdgcn_mfma_f32_16x16x32_bf16(kh0, qhi0, a, 0, 0, 0);
  a = __builtin_amdgcn_mfma_f32_16x16x32_bf16(kl0, qhi0, a, 0, 0, 0);
  a = __builtin_amdgcn_mfma_f32_16x16x32_bf16(kh0, qlo0, a, 0, 0, 0);
  a = __builtin_amdgcn_mfma_f32_16x16x32_bf16(kh1, qhi1, a, 0, 0, 0);
  a = __builtin_amdgcn_mfma_f32_16x16x32_bf16(kl1, qhi1, a, 0, 0, 0);
  a = __builtin_amdgcn_mfma_f32_16x16x32_bf16(kh1, qlo1, a, 0, 0, 0);
  float s0 = (bits4 & 1u) ? MASK_FILL : a[0];
  float s1 = (bits4 & 2u) ? MASK_FILL : a[1];
  float s2 = (bits4 & 4u) ? MASK_FILL : a[2];
  float s3 = (bits4 & 8u) ? MASK_FILL : a[3];
  float p0 = exp2f(s0 - mf) * linv;
  float p1 = exp2f(s1 - mf) * linv;
  float p2 = exp2f(s2 - mf) * linv;
  float p3 = exp2f(s3 - mf) * linv;
  floatx4 st = {p0, p1, p2, p3};
  __builtin_nontemporal_store(st, (floatx4*)attn_addr);
  TileOut o;
  o.d0 = pkbf(p0, p1);
  o.d1 = pkbf(p2, p3);
  return o;
}

__global__ __launch_bounds__(256, 4) void sdpa_main(
    const float* __restrict__ qp, const __bf16* __restrict__ khi,
    const __bf16* __restrict__ klo, const __bf16* __restrict__ vT,
    const unsigned* __restrict__ mbT, float* __restrict__ outp) {
  const int tid = threadIdx.x;
  const int lane = tid & 63;
  const int w = tid >> 6;
  const int ll = lane & 15;
  const int quad = lane >> 4;
  const int q0 = blockIdx.x * 16;
  const int bh = blockIdx.y;
  const int b = bh >> 4;

  __shared__ float red_m[4][16];
  __shared__ float red_l[4][16];
  __shared__ float outred[4][64][17];  // [wave][d][q], padded

  const size_t bh_off = (size_t)bh * (SEQ * HD);

  // q fragments (B-layout: lane ll -> q row q0+ll, k-index quad*8 -> d)
  bf16x8 qhi0, qlo0, qhi1, qlo1;
  {
    const float* qr = qp + bh_off + (size_t)(q0 + ll) * HD + quad * 8;
    split8(*(const float4*)(qr), *(const float4*)(qr + 4), QSCALE, qhi0, qlo0);
    split8(*(const float4*)(qr + 32), *(const float4*)(qr + 36), QSCALE, qhi1, qlo1);
  }

  const unsigned* mrow = mbT + (size_t)b * 64 * SEQ + (q0 + ll);

  // ---- pass 1: online (m, l); wave w owns j-tiles w*32 .. w*32+31 ----
  float m = -INFINITY, l = 0.f;
#pragma unroll 4
  for (int i = 0; i < 32; ++i) {
    const int t = w * 32 + i;
    const size_t kb = bh_off + (size_t)(t * 16 + ll) * HD + quad * 8;
    bf16x8 kh0 = *(const bf16x8*)(khi + kb), kh1 = *(const bf16x8*)(khi + kb + 32);
    bf16x8 kl0 = *(const bf16x8*)(klo + kb), kl1 = *(const bf16x8*)(klo + kb + 32);
    floatx4 a = 0.f;
    a = __builtin_amdgcn_mfma_f32_16x16x32_bf16(kh0, qhi0, a, 0, 0, 0);
    a = __builtin_amdgcn_mfma_f32_16x16x32_bf16(kl0, qhi0, a, 0, 0, 0);
    a = __builtin_amdgcn_mfma_f32_16x16x32_bf16(kh0, qlo0, a, 0, 0, 0);
    a = __builtin_amdgcn_mfma_f32_16x16x32_bf16(kh1, qhi1, a, 0, 0, 0);
    a = __builtin_amdgcn_mfma_f32_16x16x32_bf16(kl1, qhi1, a, 0, 0, 0);
    a = __builtin_amdgcn_mfma_f32_16x16x32_bf16(kh1, qlo1, a, 0, 0, 0);
    const unsigned bits = mrow[(size_t)(t >> 1) * SEQ] >> ((t & 1) * 16 + quad * 4);
    float s0 = (bits & 1u) ? MASK_FILL : a[0];
    float s1 = (bits & 2u) ? MASK_FILL : a[1];
    float s2 = (bits & 4u) ? MASK_FILL : a[2];
    float s3 = (bits & 8u) ? MASK_FILL : a[3];
    float tm = fmaxf(fmaxf(s0, s1), fmaxf(s2, s3));
    float mn = fmaxf(m, tm);
    l = l * exp2f(m - mn) +
        ((exp2f(s0 - mn) + exp2f(s1 - mn)) + (exp2f(s2 - mn) + exp2f(s3 - mn)));
    m = mn;
  }
  // combine across quads (lanes ll identical q-row): xor 16, 32
#pragma unroll
  for (int d = 16; d <= 32; d <<= 1) {
    float mo = __shfl_xor(m, d, 64);
    float lo_ = __shfl_xor(l, d, 64);
    float mn = fmaxf(m, mo);
    l = l * exp2f(m - mn) + lo_ * exp2f(mo - mn);
    m = mn;
  }
  if (lane < 16) {
    red_m[w][lane] = m;
    red_l[w][lane] = l;
  }
  __syncthreads();
  float mf = fmaxf(fmaxf(red_m[0][ll], red_m[1][ll]),
                   fmaxf(red_m[2][ll], red_m[3][ll]));
  float lf = red_l[0][ll] * exp2f(red_m[0][ll] - mf) +
             red_l[1][ll] * exp2f(red_m[1][ll] - mf) +
             red_l[2][ll] * exp2f(red_m[2][ll] - mf) +
             red_l[3][ll] * exp2f(red_m[3][ll] - mf);
  const float linv = 1.0f / lf;

  // ---- pass 2: recompute, write attn, accumulate out^T partials ----
  floatx4 o0 = 0.f, o1 = 0.f, o2 = 0.f, o3 = 0.f;
  float* attnrow = outp + (size_t)(BHN * SEQ * HD) + (size_t)bh * SEQ * SEQ +
                   (size_t)(q0 + ll) * SEQ;
  const __bf16* vb = vT + (size_t)bh * HD * SEQ;
  for (int i2 = 0; i2 < 16; ++i2) {
    const int tA = w * 32 + 2 * i2;
    const int j0 = tA * 16;
    const unsigned bits = mrow[(size_t)(tA >> 1) * SEQ];
    const size_t kbA = bh_off + (size_t)(tA * 16 + ll) * HD + quad * 8;
    const size_t kbB = kbA + (size_t)16 * HD;
    TileOut A = do_tile(khi + kbA, klo + kbA, qhi0, qlo0, qhi1, qlo1,
                        bits >> (quad * 4), mf, linv, attnrow + j0 + quad * 4);
    TileOut B = do_tile(khi + kbB, klo + kbB, qhi0, qlo0, qhi1, qlo1,
                        bits >> (16 + quad * 4), mf, linv,
                        attnrow + j0 + 16 + quad * 4);
    // repack p (C-layout rows j=quad*4+r) -> PV B-fragment (k=quad*8+jj):
    // dw0/dw1 = tile A pairs, dw2/dw3 = tile B pairs
    unsigned dw0 = A.d0, dw1 = A.d1, dw2 = B.d0, dw3 = B.d1;
    unsigned u0 = __shfl_xor(dw0, 16, 64), u1 = __shfl_xor(dw1, 16, 64);
    unsigned u2 = __shfl_xor(dw2, 16, 64), u3 = __shfl_xor(dw3, 16, 64);
    const bool qodd = (quad & 1);
    unsigned lo0 = qodd ? u0 : dw0, lo1 = qodd ? u1 : dw1;
    unsigned lo2 = qodd ? dw0 : u0, lo3 = qodd ? dw1 : u1;
    unsigned hi0 = qodd ? u2 : dw2, hi1 = qodd ? u3 : dw3;
    unsigned hi2 = qodd ? dw2 : u2, hi3 = qodd ? dw3 : u3;
    const bool qlo2 = (quad < 2);
    unsigned s0 = qlo2 ? hi0 : lo0, s1 = qlo2 ? hi1 : lo1;
    unsigned s2 = qlo2 ? hi2 : lo2, s3 = qlo2 ? hi3 : lo3;
    unsigned r0 = __shfl_xor(s0, 32, 64), r1 = __shfl_xor(s1, 32, 64);
    unsigned r2 = __shfl_xor(s2, 32, 64), r3 = __shfl_xor(s3, 32, 64);
    union { unsigned u[4]; bf16x8 v; } pf;
    pf.u[0] = (quad == 0) ? lo0 : (quad == 3) ? hi0 : r0;
    pf.u[1] = (quad == 0) ? lo1 : (quad == 3) ? hi1 : r1;
    pf.u[2] = (quad == 0) ? lo2 : (quad == 3) ? hi2 : r2;
    pf.u[3] = (quad == 0) ? lo3 : (quad == 3) ? hi3 : r3;
    // PV: out^T[d][q] += V^T[d][j] * P^T[j][q]
    const __bf16* vr = vb + (size_t)ll * SEQ + j0 + quad * 8;
    o0 = __builtin_amdgcn_mfma_f32_16x16x32_bf16(*(const bf16x8*)(vr), pf.v, o0, 0, 0, 0);
    o1 = __builtin_amdgcn_mfma_f32_16x16x32_bf16(*(const bf16x8*)(vr + 16 * SEQ), pf.v, o1, 0, 0, 0);
    o2 = __builtin_amdgcn_mfma_f32_16x16x32_bf16(*(const bf16x8*)(vr + 32 * SEQ), pf.v, o2, 0, 0, 0);
    o3 = __builtin_amdgcn_mfma_f32_16x16x32_bf16(*(const bf16x8*)(vr + 48 * SEQ), pf.v, o3, 0, 0, 0);
  }

  // ---- cross-wave reduction of out^T partials ----
#pragma unroll
  for (int r = 0; r < 4; ++r) {
    outred[w][ 0 + quad * 4 + r][ll] = o0[r];
    outred[w][16 + quad * 4 + r][ll] = o1[r];
    outred[w][32 + quad * 4 + r][ll] = o2[r];
    outred[w][48 + quad * 4 + r][ll] = o3[r];
  }
  __syncthreads();
  {
    const int qq = tid >> 4;
    const int d0 = (tid & 15) * 4;
    floatx4 res;
#pragma unroll
    for (int j = 0; j < 4; ++j)
      res[j] = outred[0][d0 + j][qq] + outred[1][d0 + j][qq] +
               outred[2][d0 + j][qq] + outred[3][d0 + j][qq];
    __builtin_nontemporal_store(
        res, (floatx4*)(outp + bh_off + (size_t)(q0 + qq) * HD + d0));
  }
}

// ---------------- fallback (round-0 kernel, verified 2230us) ----------------

__global__ __launch_bounds__(256, 2) void sdpa_fallback(
    const float* __restrict__ qp, const float* __restrict__ kp,
    const float* __restrict__ vp, const int* __restrict__ maskp,
    float* __restrict__ outp) {
  const int tid  = threadIdx.x;
  const int lane = tid & 63;
  const int w    = tid >> 6;
  const int ll   = lane & 15;
  const int quad = lane >> 4;
  const int q0   = blockIdx.x * 16;
  const int bh   = blockIdx.y;
  const int b    = bh >> 4;

  __shared__ __align__(16) __bf16 vT[64][264];
  __shared__ __align__(16) __bf16 pC[16][264];
  __shared__ float red_m[4][16];
  __shared__ float red_l[4][16];

  const size_t bh_off = (size_t)bh * (SEQ * HD);

  bf16x8 qhi0, qlo0, qhi1, qlo1;
  {
    const float* qr = qp + bh_off + (size_t)(q0 + ll) * HD + quad * 8;
    float4 a0 = *(const float4*)(qr);
    float4 a1 = *(const float4*)(qr + 4);
    float4 a2 = *(const float4*)(qr + 32);
    float4 a3 = *(const float4*)(qr + 36);
    split8(a0, a1, 0.125f, qhi0, qlo0);
    split8(a2, a3, 0.125f, qhi1, qlo1);
  }

  floatx4 acc[32];
#pragma unroll
  for (int i = 0; i < 32; ++i) acc[i] = 0.f;

  const float* kb = kp + bh_off;
#pragma unroll
  for (int i = 0; i < 32; ++i) {
    const int col0 = (4 * i + w) * 16;
    const float* kr = kb + (size_t)(col0 + ll) * HD + quad * 8;
    float4 a0 = *(const float4*)(kr);
    float4 a1 = *(const float4*)(kr + 4);
    float4 a2 = *(const float4*)(kr + 32);
    float4 a3 = *(const float4*)(kr + 36);
    bf16x8 khi0, klo0, khi1, klo1;
    split8(a0, a1, 1.f, khi0, klo0);
    split8(a2, a3, 1.f, khi1, klo1);
    floatx4 t = acc[i];
    t = __builtin_amdgcn_mfma_f32_16x16x32_bf16(qhi0, khi0, t, 0, 0, 0);
    t = __builtin_amdgcn_mfma_f32_16x16x32_bf16(qlo0, khi0, t, 0, 0, 0);
    t = __builtin_amdgcn_mfma_f32_16x16x32_bf16(qhi0, klo0, t, 0, 0, 0);
    t = __builtin_amdgcn_mfma_f32_16x16x32_bf16(qhi1, khi1, t, 0, 0, 0);
    t = __builtin_amdgcn_mfma_f32_16x16x32_bf16(qlo1, khi1, t, 0, 0, 0);
    t = __builtin_amdgcn_mfma_f32_16x16x32_bf16(qhi1, klo1, t, 0, 0, 0);
    acc[i] = t;
  }

  const int* mb = maskp + (size_t)b * SEQ * SEQ;
  float mx[4] = {-INFINITY, -INFINITY, -INFINITY, -INFINITY};
#pragma unroll
  for (int i = 0; i < 32; ++i) {
    const int col = (4 * i + w) * 16 + ll;
#pragma unroll
    for (int r = 0; r < 4; ++r) {
      const int row = q0 + quad * 4 + r;
      const int mv = mb[(size_t)row * SEQ + col];
      float sv = mv ? -1e9f : acc[i][r];
      acc[i][r] = sv;
      mx[r] = fmaxf(mx[r], sv);
    }
  }
#pragma unroll
  for (int d = 1; d < 16; d <<= 1) {
#pragma unroll
    for (int r = 0; r < 4; ++r) mx[r] = fmaxf(mx[r], __shfl_xor(mx[r], d, 64));
  }
  if (ll == 0) {
#pragma unroll
    for (int r = 0; r < 4; ++r) red_m[w][quad * 4 + r] = mx[r];
  }
  __syncthreads();
  float mrow[4];
#pragma unroll
  for (int r = 0; r < 4; ++r) {
    const int row = quad * 4 + r;
    mrow[r] = fmaxf(fmaxf(red_m[0][row], red_m[1][row]),
                    fmaxf(red_m[2][row], red_m[3][row]));
  }

  float sm[4] = {0.f, 0.f, 0.f, 0.f};
#pragma unroll
  for (int i = 0; i < 32; ++i) {
#pragma unroll
    for (int r = 0; r < 4; ++r) {
      float e = __expf(acc[i][r] - mrow[r]);
      acc[i][r] = e;
      sm[r] += e;
    }
  }
#pragma unroll
  for (int d = 1; d < 16; d <<= 1) {
#pragma unroll
    for (int r = 0; r < 4; ++r) sm[r] += __shfl_xor(sm[r], d, 64);
  }
  if (ll == 0) {
#pragma unroll
    for (int r = 0; r < 4; ++r) red_l[w][quad * 4 + r] = sm[r];
  }
  __syncthreads();
  float linv[4];
#pragma unroll
  for (int r = 0; r < 4; ++r) {
    const int row = quad * 4 + r;
    linv[r] = 1.0f / (red_l[0][row] + red_l[1][row] + red_l[2][row] + red_l[3][row]);
  }

  float* attn = outp + (size_t)(NB * NH * SEQ * HD) + (size_t)bh * SEQ * SEQ;
#pragma unroll
  for (int i = 0; i < 32; ++i) {
    const int col = (4 * i + w) * 16 + ll;
#pragma unroll
    for (int r = 0; r < 4; ++r) {
      const int row = q0 + quad * 4 + r;
      float p = acc[i][r] * linv[r];
      acc[i][r] = p;
      attn[(size_t)row * SEQ + col] = p;
    }
  }

  floatx4 oacc = 0.f;
  const float* vb = vp + bh_off;
#pragma unroll
  for (int c = 0; c < 8; ++c) {
    {
      const float* vr = vb + (size_t)(c * 256 + tid) * HD;
#pragma unroll
      for (int d4 = 0; d4 < 16; ++d4) {
        float4 vv = *(const float4*)(vr + d4 * 4);
        vT[d4 * 4 + 0][tid] = (__bf16)vv.x;
        vT[d4 * 4 + 1][tid] = (__bf16)vv.y;
        vT[d4 * 4 + 2][tid] = (__bf16)vv.z;
        vT[d4 * 4 + 3][tid] = (__bf16)vv.w;
      }
    }
#pragma unroll
    for (int u = 0; u < 4; ++u) {
      const int lt = w + 4 * u;
#pragma unroll
      for (int r = 0; r < 4; ++r)
        pC[quad * 4 + r][lt * 16 + ll] = (__bf16)acc[4 * c + u][r];
    }
    __syncthreads();
#pragma unroll
    for (int kk = 0; kk < 8; ++kk) {
      bf16x8 af = *(const bf16x8*)&pC[ll][kk * 32 + quad * 8];
      bf16x8 bf = *(const bf16x8*)&vT[w * 16 + ll][kk * 32 + quad * 8];
      oacc = __builtin_amdgcn_mfma_f32_16x16x32_bf16(af, bf, oacc, 0, 0, 0);
    }
    __syncthreads();
  }

  float* ob = outp + bh_off + (size_t)q0 * HD;
#pragma unroll
  for (int r = 0; r < 4; ++r)
    ob[(size_t)(quad * 4 + r) * HD + w * 16 + ll] = oacc[r];
}

extern "C" void kernel_launch(void* const* d_in, const int* in_sizes, int n_in,
                              void* d_out, int out_size, void* d_ws, size_t ws_size,
                              hipStream_t stream) {
  const float* q = (const float*)d_in[0];
  const float* k = (const float*)d_in[1];
  const float* v = (const float*)d_in[2];
  const int* mask = (const int*)d_in[3];
  float* out = (float*)d_out;

  if (ws_size < WS_REQUIRED || d_ws == nullptr) {
    // not enough workspace: run the verified round-0 kernel
    dim3 grid(SEQ / 16, NB * NH);
    sdpa_fallback<<<grid, dim3(256), 0, stream>>>(q, k, v, mask, out);
    return;
  }

  // workspace layout: khi[KN] | klo[KN] | vT[KN] | mbT (bf16,bf16,bf16,u32)
  __bf16* khi = (__bf16*)d_ws;
  __bf16* klo = khi + KN;
  __bf16* vT = klo + KN;
  unsigned* mbT = (unsigned*)(vT + KN);  // NB*64*SEQ u32 = 2 MB; total ~52.4 MB

  prep_splitk<<<4096, 256, 0, stream>>>(k, khi, klo);
  prep_vt<<<2048, 256, 0, stream>>>(v, vT);
  prep_mask<<<65536, 256, 0, stream>>>(mask, mbT);
  sdpa_main<<<dim3(SEQ / 16, BHN), dim3(256), 0, stream>>>(q, khi, klo, vT, mbT, out);
}